// Round 1
// baseline (776.442 us; speedup 1.0000x reference)
//
#include <hip/hip_runtime.h>
#include <hip/hip_bf16.h>

#define TB 2048
#define NH 16
#define HD 64
#define NE 1024
#define NB 4
#define BHD (NB * NH)      // 64 batch*heads
#define MTOK (NB * TB)     // 8192

typedef __attribute__((ext_vector_type(8))) short short8;
typedef __attribute__((ext_vector_type(4))) float f32x4;

static __device__ __forceinline__ unsigned short f2bf(float f) {
  __hip_bfloat16 h = __float2bfloat16(f);
  return __builtin_bit_cast(unsigned short, h);
}

// ---------------- f32 -> bf16 convert (vectorized) ----------------
__global__ __launch_bounds__(256) void cvt_kernel(const float* __restrict__ in,
                                                  unsigned short* __restrict__ out,
                                                  int n4) {
  int i = blockIdx.x * blockDim.x + threadIdx.x;
  if (i >= n4) return;
  float4 v = reinterpret_cast<const float4*>(in)[i];
  ushort4 o;
  o.x = f2bf(v.x); o.y = f2bf(v.y); o.z = f2bf(v.z); o.w = f2bf(v.w);
  reinterpret_cast<ushort4*>(out)[i] = o;
}

// ---------------- GEMM C = A * B^T (A:[M][K] bf16, B:[N][K] bf16) ----------------
// 128x128 tile, BK=64, 4 waves (2x2), each wave 64x64 via 4x4 frags of 16x16x32.
// LDS XOR-swizzled (16B-chunk index ^ (row&7)); staging via global_load_lds with
// pre-swizzled per-lane global source (linear LDS dest requirement).
#define GLDS(g, l)                                                              \
  __builtin_amdgcn_global_load_lds((const __attribute__((address_space(1))) void*)(g), \
                                   (__attribute__((address_space(3))) void*)(l), 16, 0, 0)

template <int EPI>  // 0: plain f32 C store; 1: QKV epilogue (RoPE + scatter)
__global__ __launch_bounds__(256) void gemm_bt(
    const unsigned short* __restrict__ Am, const unsigned short* __restrict__ Bm,
    float* __restrict__ Cout, unsigned short* __restrict__ Qo,
    unsigned short* __restrict__ Ko, unsigned short* __restrict__ Vt,
    int Mdim, int Ndim, int Kdim) {
  __shared__ unsigned short As[128 * 64];
  __shared__ unsigned short Bs[128 * 64];

  const int tid = threadIdx.x;
  const int lane = tid & 63;
  const int w = tid >> 6;
  const int wr = w >> 1;
  const int wc = w & 1;
  const int m0 = blockIdx.y * 128;
  const int n0 = blockIdx.x * 128;
  const int col16 = lane & 15;
  const int seg = lane >> 4;

  f32x4 acc[4][4];
#pragma unroll
  for (int i = 0; i < 4; ++i)
#pragma unroll
    for (int j = 0; j < 4; ++j) acc[i][j] = f32x4{0.f, 0.f, 0.f, 0.f};

  const int lrow = lane >> 3;            // row within 8-row chunk
  const int jg = (lane & 7) ^ lrow;      // pre-swizzled 16B-chunk col in global

  for (int kt = 0; kt < Kdim; kt += 64) {
#pragma unroll
    for (int i = 0; i < 4; ++i) {
      const int q = w * 4 + i;           // 1KB chunk id (0..15)
      const int row = q * 8 + lrow;      // tile row 0..127  (row&7 == lrow)
      GLDS(Am + (size_t)(m0 + row) * Kdim + kt + jg * 8, As + q * 512);
      GLDS(Bm + (size_t)(n0 + row) * Kdim + kt + jg * 8, Bs + q * 512);
    }
    __syncthreads();
#pragma unroll
    for (int kk = 0; kk < 2; ++kk) {
      short8 af[4], bfr[4];
#pragma unroll
      for (int mi = 0; mi < 4; ++mi) {
        const int row = wr * 64 + mi * 16 + col16;
        const int ch = (kk * 4 + seg) ^ (row & 7);
        af[mi] = *reinterpret_cast<const short8*>(
            reinterpret_cast<const char*>(As) + row * 128 + ch * 16);
      }
#pragma unroll
      for (int ni = 0; ni < 4; ++ni) {
        const int row = wc * 64 + ni * 16 + col16;
        const int ch = (kk * 4 + seg) ^ (row & 7);
        bfr[ni] = *reinterpret_cast<const short8*>(
            reinterpret_cast<const char*>(Bs) + row * 128 + ch * 16);
      }
#pragma unroll
      for (int mi = 0; mi < 4; ++mi)
#pragma unroll
        for (int ni = 0; ni < 4; ++ni)
          acc[mi][ni] = __builtin_amdgcn_mfma_f32_16x16x32_bf16(af[mi], bfr[ni],
                                                                acc[mi][ni], 0, 0, 0);
    }
    __syncthreads();
  }

  if (EPI == 0) {
#pragma unroll
    for (int mi = 0; mi < 4; ++mi)
#pragma unroll
      for (int ni = 0; ni < 4; ++ni) {
        const int gn = n0 + wc * 64 + ni * 16 + col16;
#pragma unroll
        for (int r = 0; r < 4; ++r) {
          const int gm = m0 + wr * 64 + mi * 16 + seg * 4 + r;
          Cout[(size_t)gm * Ndim + gn] = acc[mi][ni][r];
        }
      }
  } else {
    // qkv: n in [0,1024)=Q, [1024,2048)=K, [2048,3072)=V. 128|1024 so sec uniform.
    const int sec = n0 >> 10;
    const int cbase = (n0 & 1023) + wc * 64;  // multiple of 64
    const int h = cbase >> 6;
#pragma unroll
    for (int mi = 0; mi < 4; ++mi)
#pragma unroll
      for (int ni = 0; ni < 4; ++ni) {
        const int d = ni * 16 + col16;  // 0..63 head dim
        if (sec == 2) {
          // V: store transposed [BH][D][T]; 4 consecutive t per lane -> 8B store
          const int gm0 = m0 + wr * 64 + mi * 16 + seg * 4;
          const int b = gm0 >> 11;
          const int t0 = gm0 & 2047;
          ushort4 pv;
          pv.x = f2bf(acc[mi][ni][0]);
          pv.y = f2bf(acc[mi][ni][1]);
          pv.z = f2bf(acc[mi][ni][2]);
          pv.w = f2bf(acc[mi][ni][3]);
          *reinterpret_cast<ushort4*>(
              Vt + ((size_t)((b * NH + h) * HD + d)) * TB + t0) = pv;
        } else {
          // RoPE: out[2i]   = x[2i]*cos(a_{2i})   - x[2i+1]*sin(a_{2i})
          //       out[2i+1] = x[2i+1]*cos(a_{2i+1}) + x[2i]*sin(a_{2i+1})
          // angle a_d = t * 10000^(-(d%32)/32)
          const float sgn = (d & 1) ? 1.f : -1.f;
          const float invf =
              __builtin_exp2f(-(float)(d & 31) * 0.41524101186092029f);
#pragma unroll
          for (int r = 0; r < 4; ++r) {
            const int gm = m0 + wr * 64 + mi * 16 + seg * 4 + r;
            const int b = gm >> 11;
            const int t = gm & 2047;
            const float v = acc[mi][ni][r];
            const float p = __shfl_xor(v, 1);  // pair partner (adjacent col)
            float sv, cv;
            sincosf((float)t * invf, &sv, &cv);
            float rot = v * cv + sgn * p * sv;
            if (sec == 0) rot *= 0.125f;  // fold 1/sqrt(D) into Q (exact)
            unsigned short* dst = (sec == 0) ? Qo : Ko;
            dst[((size_t)(b * NH + h) * TB + t) * HD + d] = f2bf(rot);
          }
        }
      }
  }
}

// ---------------- causal flash attention ----------------
// grid (T/64, BH), 256 threads = 4 waves; wave w owns 16 q rows; KV tiles of 64.
// Q pre-scaled by 1/8. K:[BH][T][D], Vt:[BH][D][T] so all MFMA fragments are
// contiguous 16B global loads. P transposed via per-wave XOR-swizzled LDS.
__global__ __launch_bounds__(256) void attn_kernel(
    const unsigned short* __restrict__ Q, const unsigned short* __restrict__ K,
    const unsigned short* __restrict__ Vt, unsigned short* __restrict__ Ao) {
  __shared__ unsigned short Plds[4][16 * 64];

  const int bh = blockIdx.y;
  const int qi = (int)gridDim.x - 1 - (int)blockIdx.x;  // long blocks first
  const int tid = threadIdx.x;
  const int lane = tid & 63;
  const int w = tid >> 6;
  const int col16 = lane & 15;
  const int seg = lane >> 4;

  const unsigned short* Qb = Q + (size_t)bh * TB * HD;
  const unsigned short* Kb = K + (size_t)bh * TB * HD;
  const unsigned short* Vb = Vt + (size_t)bh * HD * TB;
  const int q0 = qi * 64 + w * 16;

  short8 aq[2];
#pragma unroll
  for (int kk = 0; kk < 2; ++kk)
    aq[kk] = *reinterpret_cast<const short8*>(Qb + (size_t)(q0 + col16) * HD +
                                              kk * 32 + seg * 8);

  float mrow[4], lsum[4];
  f32x4 o[4];
#pragma unroll
  for (int r = 0; r < 4; ++r) { mrow[r] = -1e30f; lsum[r] = 0.f; }
#pragma unroll
  for (int df = 0; df < 4; ++df) o[df] = f32x4{0.f, 0.f, 0.f, 0.f};

  char* myP = reinterpret_cast<char*>(&Plds[w][0]);

  for (int kt = 0; kt <= qi; ++kt) {
    const int kv0 = kt * 64;
    f32x4 s[4];
#pragma unroll
    for (int nf = 0; nf < 4; ++nf) s[nf] = f32x4{0.f, 0.f, 0.f, 0.f};

#pragma unroll
    for (int nf = 0; nf < 4; ++nf) {
      const unsigned short* kp =
          Kb + (size_t)(kv0 + nf * 16 + col16) * HD + seg * 8;
#pragma unroll
      for (int kk = 0; kk < 2; ++kk) {
        short8 bk = *reinterpret_cast<const short8*>(kp + kk * 32);
        s[nf] = __builtin_amdgcn_mfma_f32_16x16x32_bf16(aq[kk], bk, s[nf], 0, 0, 0);
      }
    }

    if (kt == qi) {  // diagonal tile: mask kg > qg
#pragma unroll
      for (int nf = 0; nf < 4; ++nf) {
        const int kg = kv0 + nf * 16 + col16;
#pragma unroll
        for (int r = 0; r < 4; ++r) {
          const int qg = q0 + seg * 4 + r;
          if (kg > qg) s[nf][r] = -1e30f;
        }
      }
    }

    // online softmax: row groups are 16 consecutive lanes (butterfly xor 1,2,4,8)
    float pm[4];
#pragma unroll
    for (int r = 0; r < 4; ++r) {
      pm[r] = fmaxf(fmaxf(s[0][r], s[1][r]), fmaxf(s[2][r], s[3][r]));
#pragma unroll
      for (int x = 1; x < 16; x <<= 1) pm[r] = fmaxf(pm[r], __shfl_xor(pm[r], x));
    }
    float fs[4];
#pragma unroll
    for (int r = 0; r < 4; ++r) {
      const float mn = fmaxf(mrow[r], pm[r]);
      fs[r] = __expf(mrow[r] - mn);
      mrow[r] = mn;
    }
#pragma unroll
    for (int nf = 0; nf < 4; ++nf)
#pragma unroll
      for (int r = 0; r < 4; ++r) s[nf][r] = __expf(s[nf][r] - mrow[r]);
#pragma unroll
    for (int r = 0; r < 4; ++r) {
      float rs = s[0][r] + s[1][r] + s[2][r] + s[3][r];
#pragma unroll
      for (int x = 1; x < 16; x <<= 1) rs += __shfl_xor(rs, x);
      lsum[r] = lsum[r] * fs[r] + rs;
    }
#pragma unroll
    for (int df = 0; df < 4; ++df)
#pragma unroll
      for (int r = 0; r < 4; ++r) o[df][r] *= fs[r];

    // P -> bf16 -> per-wave LDS (XOR-swizzled, no barrier: wave-private buffer)
#pragma unroll
    for (int nf = 0; nf < 4; ++nf)
#pragma unroll
      for (int r = 0; r < 4; ++r) {
        const int prow = seg * 4 + r;
        const int pcol = nf * 16 + col16;
        const int byteoff = prow * 128 + ((pcol * 2) ^ ((prow & 7) << 4));
        *reinterpret_cast<unsigned short*>(myP + byteoff) = f2bf(s[nf][r]);
      }

    // PV: A-frag = P[qrow=lane&15][k=seg*8+j], B-frag = Vt[d][kv] contiguous
#pragma unroll
    for (int kk = 0; kk < 2; ++kk) {
      const int prow = col16;
      const int pb = prow * 128 + (((kk * 4 + seg) * 16) ^ ((prow & 7) << 4));
      short8 pa = *reinterpret_cast<const short8*>(myP + pb);
#pragma unroll
      for (int df = 0; df < 4; ++df) {
        const int d = df * 16 + col16;
        short8 bv = *reinterpret_cast<const short8*>(
            Vb + (size_t)d * TB + kv0 + kk * 32 + seg * 8);
        o[df] = __builtin_amdgcn_mfma_f32_16x16x32_bf16(pa, bv, o[df], 0, 0, 0);
      }
    }
  }

  // normalize + store bf16 [B][T][E]
  const int b = bh >> 4;
  const int h = bh & 15;
#pragma unroll
  for (int r = 0; r < 4; ++r) {
    const float inv = 1.f / lsum[r];
    const int t = q0 + seg * 4 + r;
#pragma unroll
    for (int df = 0; df < 4; ++df) {
      const int c = h * 64 + df * 16 + col16;
      Ao[((size_t)(b * TB + t)) * NE + c] = f2bf(o[df][r] * inv);
    }
  }
}

// ---------------- launch ----------------
extern "C" void kernel_launch(void* const* d_in, const int* in_sizes, int n_in,
                              void* d_out, int out_size, void* d_ws, size_t ws_size,
                              hipStream_t stream) {
  const float* x = (const float*)d_in[0];
  const float* w_attn = (const float*)d_in[1];
  const float* w_proj = (const float*)d_in[2];
  float* out = (float*)d_out;
  char* ws = (char*)d_ws;

  const size_t SZ_XB = (size_t)MTOK * NE * 2;        // 16 MiB
  const size_t SZ_WA = (size_t)3 * NE * NE * 2;      // 6 MiB
  const size_t SZ_WP = (size_t)NE * NE * 2;          // 2 MiB
  const size_t SZ_T = (size_t)BHD * TB * HD * 2;     // 16 MiB

  unsigned short* xb = (unsigned short*)(ws);
  unsigned short* wab = (unsigned short*)(ws + SZ_XB);
  unsigned short* wpb = (unsigned short*)(ws + SZ_XB + SZ_WA);
  unsigned short* Qs = (unsigned short*)(ws + SZ_XB + SZ_WA + SZ_WP);
  unsigned short* Ks = (unsigned short*)(ws + SZ_XB + SZ_WA + SZ_WP + SZ_T);
  unsigned short* Vt = (unsigned short*)(ws + SZ_XB + SZ_WA + SZ_WP + 2 * SZ_T);
  unsigned short* Ao = (unsigned short*)(ws + SZ_XB + SZ_WA + SZ_WP + 3 * SZ_T);

  hipLaunchKernelGGL(cvt_kernel, dim3(MTOK * NE / 4 / 256), dim3(256), 0, stream,
                     x, xb, MTOK * NE / 4);
  hipLaunchKernelGGL(cvt_kernel, dim3(3 * NE * NE / 4 / 256), dim3(256), 0, stream,
                     w_attn, wab, 3 * NE * NE / 4);
  hipLaunchKernelGGL(cvt_kernel, dim3(NE * NE / 4 / 256), dim3(256), 0, stream,
                     w_proj, wpb, NE * NE / 4);

  hipLaunchKernelGGL((gemm_bt<1>), dim3(3 * NE / 128, MTOK / 128), dim3(256), 0,
                     stream, xb, wab, nullptr, Qs, Ks, Vt, MTOK, 3 * NE, NE);

  hipLaunchKernelGGL(attn_kernel, dim3(TB / 64, BHD), dim3(256), 0, stream,
                     Qs, Ks, Vt, Ao);

  hipLaunchKernelGGL((gemm_bt<0>), dim3(NE / 128, MTOK / 128), dim3(256), 0,
                     stream, Ao, wpb, out, nullptr, nullptr, nullptr, MTOK, NE, NE);
}

// Round 3
// 340.828 us; speedup vs baseline: 2.2781x; 2.2781x over previous
//
#include <hip/hip_runtime.h>
#include <hip/hip_bf16.h>

#define TB 2048
#define NH 16
#define HD 64
#define NE 1024
#define NB 4
#define BHD (NB * NH)      // 64 batch*heads
#define MTOK (NB * TB)     // 8192

typedef __attribute__((ext_vector_type(8))) short short8;
typedef __attribute__((ext_vector_type(4))) float f32x4;

static __device__ __forceinline__ unsigned short f2bf(float f) {
  __hip_bfloat16 h = __float2bfloat16(f);
  return __builtin_bit_cast(unsigned short, h);
}

#define GLDS(g, l)                                                              \
  __builtin_amdgcn_global_load_lds((const __attribute__((address_space(1))) void*)(g), \
                                   (__attribute__((address_space(3))) void*)(l), 16, 0, 0)

// ---------------- f32 -> bf16 convert (vectorized) ----------------
__global__ __launch_bounds__(256) void cvt_kernel(const float* __restrict__ in,
                                                  unsigned short* __restrict__ out,
                                                  int n4) {
  int i = blockIdx.x * blockDim.x + threadIdx.x;
  if (i >= n4) return;
  float4 v = reinterpret_cast<const float4*>(in)[i];
  ushort4 o;
  o.x = f2bf(v.x); o.y = f2bf(v.y); o.z = f2bf(v.z); o.w = f2bf(v.w);
  reinterpret_cast<ushort4*>(out)[i] = o;
}

// ---------------- RoPE cos/sin table: tab[t*32+j] = (cos, sin)(t * 10000^(-j/32)) ----------------
__global__ __launch_bounds__(256) void rope_tab_kernel(float2* __restrict__ tab) {
  int i = blockIdx.x * 256 + threadIdx.x;  // 0..65535
  int t = i >> 5, j = i & 31;
  float ang = (float)t * __builtin_exp2f(-(float)j * 0.41524101186092029f);
  float sv, cv;
  sincosf(ang, &sv, &cv);
  tab[i] = make_float2(cv, sv);
}

// ---------------- GEMM C = A * B^T (A:[M][K] bf16, B:[N][K] bf16) ----------------
template <int EPI>  // 0: plain f32 C store; 1: QKV epilogue (RoPE + scatter)
__global__ __launch_bounds__(256) void gemm_bt(
    const unsigned short* __restrict__ Am, const unsigned short* __restrict__ Bm,
    float* __restrict__ Cout, unsigned short* __restrict__ Qo,
    unsigned short* __restrict__ Ko, unsigned short* __restrict__ Vt,
    const float2* __restrict__ Tab, int Mdim, int Ndim, int Kdim) {
  __shared__ unsigned short As[128 * 64];
  __shared__ unsigned short Bs[128 * 64];

  const int tid = threadIdx.x;
  const int lane = tid & 63;
  const int w = tid >> 6;
  const int wr = w >> 1;
  const int wc = w & 1;
  const int m0 = blockIdx.y * 128;
  const int n0 = blockIdx.x * 128;
  const int col16 = lane & 15;
  const int seg = lane >> 4;

  f32x4 acc[4][4];
#pragma unroll
  for (int i = 0; i < 4; ++i)
#pragma unroll
    for (int j = 0; j < 4; ++j) acc[i][j] = f32x4{0.f, 0.f, 0.f, 0.f};

  const int lrow = lane >> 3;            // row within 8-row chunk
  const int jg = (lane & 7) ^ lrow;      // pre-swizzled 16B-chunk col in global

  for (int kt = 0; kt < Kdim; kt += 64) {
#pragma unroll
    for (int i = 0; i < 4; ++i) {
      const int q = w * 4 + i;           // 1KB chunk id (0..15)
      const int row = q * 8 + lrow;      // tile row 0..127  (row&7 == lrow)
      GLDS(Am + (size_t)(m0 + row) * Kdim + kt + jg * 8, As + q * 512);
      GLDS(Bm + (size_t)(n0 + row) * Kdim + kt + jg * 8, Bs + q * 512);
    }
    __syncthreads();
#pragma unroll
    for (int kk = 0; kk < 2; ++kk) {
      short8 af[4], bfr[4];
#pragma unroll
      for (int mi = 0; mi < 4; ++mi) {
        const int row = wr * 64 + mi * 16 + col16;
        const int ch = (kk * 4 + seg) ^ (row & 7);
        af[mi] = *reinterpret_cast<const short8*>(
            reinterpret_cast<const char*>(As) + row * 128 + ch * 16);
      }
#pragma unroll
      for (int ni = 0; ni < 4; ++ni) {
        const int row = wc * 64 + ni * 16 + col16;
        const int ch = (kk * 4 + seg) ^ (row & 7);
        bfr[ni] = *reinterpret_cast<const short8*>(
            reinterpret_cast<const char*>(Bs) + row * 128 + ch * 16);
      }
#pragma unroll
      for (int mi = 0; mi < 4; ++mi)
#pragma unroll
        for (int ni = 0; ni < 4; ++ni)
          acc[mi][ni] = __builtin_amdgcn_mfma_f32_16x16x32_bf16(af[mi], bfr[ni],
                                                                acc[mi][ni], 0, 0, 0);
    }
    __syncthreads();
  }

  if (EPI == 0) {
#pragma unroll
    for (int mi = 0; mi < 4; ++mi)
#pragma unroll
      for (int ni = 0; ni < 4; ++ni) {
        const int gn = n0 + wc * 64 + ni * 16 + col16;
#pragma unroll
        for (int r = 0; r < 4; ++r) {
          const int gm = m0 + wr * 64 + mi * 16 + seg * 4 + r;
          Cout[(size_t)gm * Ndim + gn] = acc[mi][ni][r];
        }
      }
  } else {
    // qkv: n in [0,1024)=Q, [1024,2048)=K, [2048,3072)=V. 128|1024 so sec uniform.
    const int sec = n0 >> 10;
    const int cbase = (n0 & 1023) + wc * 64;  // multiple of 64
    const int h = cbase >> 6;
#pragma unroll
    for (int mi = 0; mi < 4; ++mi)
#pragma unroll
      for (int ni = 0; ni < 4; ++ni) {
        const int d = ni * 16 + col16;  // 0..63 head dim
        if (sec == 2) {
          // V: store transposed [BH][D][T]; 4 consecutive t per lane -> 8B store
          const int gm0 = m0 + wr * 64 + mi * 16 + seg * 4;
          const int b = gm0 >> 11;
          const int t0 = gm0 & 2047;
          ushort4 pv;
          pv.x = f2bf(acc[mi][ni][0]);
          pv.y = f2bf(acc[mi][ni][1]);
          pv.z = f2bf(acc[mi][ni][2]);
          pv.w = f2bf(acc[mi][ni][3]);
          *reinterpret_cast<ushort4*>(
              Vt + ((size_t)((b * NH + h) * HD + d)) * TB + t0) = pv;
        } else {
          // RoPE via precomputed table: angle a_d = t * 10000^(-(d%32)/32)
          const float sgn = (d & 1) ? 1.f : -1.f;
          const int j = d & 31;
#pragma unroll
          for (int r = 0; r < 4; ++r) {
            const int gm = m0 + wr * 64 + mi * 16 + seg * 4 + r;
            const int b = gm >> 11;
            const int t = gm & 2047;
            const float v = acc[mi][ni][r];
            const float p = __shfl_xor(v, 1);  // pair partner (adjacent col)
            const float2 csv = Tab[t * 32 + j];
            float rot = v * csv.x + sgn * p * csv.y;
            if (sec == 0) rot *= 0.125f;  // fold 1/sqrt(D) into Q (exact)
            unsigned short* dst = (sec == 0) ? Qo : Ko;
            dst[((size_t)(b * NH + h) * TB + t) * HD + d] = f2bf(rot);
          }
        }
      }
  }
}

// ---------------- causal flash attention (cooperative, double-buffered LDS) ----------------
// grid (T/128, BH), 256 thr = 4 waves; block owns 128 q rows (wave w: 32 rows).
// KV tiles of 64 staged to LDS via global_load_lds (XOR-swizzled source), dbuf,
// one barrier per tile. Q pre-scaled by 1/8. K:[BH][T][D], Vt:[BH][D][T].
__global__ __launch_bounds__(256) void attn_kernel(
    const unsigned short* __restrict__ Q, const unsigned short* __restrict__ K,
    const unsigned short* __restrict__ Vt, unsigned short* __restrict__ Ao) {
  __shared__ unsigned short KsL[2][64 * 64];  // [buf][kv][d] swizzled
  __shared__ unsigned short VsL[2][64 * 64];  // [buf][d][kv] swizzled
  __shared__ unsigned short PsL[4][32 * 32];  // per-wave P half-tile, swizzled

  const int bh = blockIdx.y;
  const int qi = (int)gridDim.x - 1 - (int)blockIdx.x;  // long blocks first
  const int tid = threadIdx.x;
  const int lane = tid & 63;
  const int w = tid >> 6;
  const int col16 = lane & 15;
  const int seg = lane >> 4;

  const unsigned short* Qb = Q + (size_t)bh * TB * HD;
  const unsigned short* Kb = K + (size_t)bh * TB * HD;
  const unsigned short* Vb = Vt + (size_t)bh * HD * TB;
  const int q0w = qi * 128 + w * 32;

  // Q fragments: rows q0w + mi*16 + col16, k = kk*32 + seg*8
  short8 aq[2][2];
#pragma unroll
  for (int mi = 0; mi < 2; ++mi)
#pragma unroll
    for (int kk = 0; kk < 2; ++kk)
      aq[mi][kk] = *reinterpret_cast<const short8*>(
          Qb + (size_t)(q0w + mi * 16 + col16) * HD + kk * 32 + seg * 8);

  float mrow[2][4], lsum[2][4];
  f32x4 o[2][4];  // [mi][df]
#pragma unroll
  for (int mi = 0; mi < 2; ++mi)
#pragma unroll
    for (int r = 0; r < 4; ++r) { mrow[mi][r] = -1e30f; lsum[mi][r] = 0.f; }
#pragma unroll
  for (int mi = 0; mi < 2; ++mi)
#pragma unroll
    for (int df = 0; df < 4; ++df) o[mi][df] = f32x4{0.f, 0.f, 0.f, 0.f};

  char* myP = reinterpret_cast<char*>(&PsL[w][0]);
  const int nt = 2 * qi + 2;

#define STAGE_KV(bufb, tt)                                                      \
  {                                                                             \
    const int kv0s = (tt) * 64;                                                 \
    _Pragma("unroll") for (int i_ = 0; i_ < 2; ++i_) {                          \
      const int c_ = i_ * 256 + tid;                                            \
      const int row_ = c_ >> 3;                                                 \
      const int sc_ = (c_ & 7) ^ (row_ & 7);                                    \
      const int cb_ = (i_ * 256 + w * 64) * 8;                                  \
      GLDS(Kb + (size_t)(kv0s + row_) * HD + sc_ * 8, &KsL[bufb][cb_]);         \
      GLDS(Vb + (size_t)row_ * TB + kv0s + sc_ * 8, &VsL[bufb][cb_]);           \
    }                                                                           \
  }

  STAGE_KV(0, 0);
  __syncthreads();

  int cur = 0;
  for (int kt = 0; kt < nt; ++kt) {
    if (kt + 1 < nt) STAGE_KV(cur ^ 1, kt + 1);

    const int kv0 = kt * 64;
    if (kv0 <= q0w + 31) {  // not fully masked for this wave
      f32x4 s[2][4];
#pragma unroll
      for (int mi = 0; mi < 2; ++mi)
#pragma unroll
        for (int nf = 0; nf < 4; ++nf) s[mi][nf] = f32x4{0.f, 0.f, 0.f, 0.f};

      // QK^T from LDS K
#pragma unroll
      for (int kk = 0; kk < 2; ++kk)
#pragma unroll
        for (int nf = 0; nf < 4; ++nf) {
          const int rv = nf * 16 + col16;
          const int cc = (kk * 4 + seg) ^ (rv & 7);
          short8 bk = *reinterpret_cast<const short8*>(
              reinterpret_cast<const char*>(&KsL[cur][0]) + rv * 128 + cc * 16);
#pragma unroll
          for (int mi = 0; mi < 2; ++mi)
            s[mi][nf] = __builtin_amdgcn_mfma_f32_16x16x32_bf16(aq[mi][kk], bk,
                                                                s[mi][nf], 0, 0, 0);
        }

      if (kv0 + 63 > q0w) {  // diagonal region: mask kg > qg
#pragma unroll
        for (int mi = 0; mi < 2; ++mi)
#pragma unroll
          for (int nf = 0; nf < 4; ++nf) {
            const int kg = kv0 + nf * 16 + col16;
#pragma unroll
            for (int r = 0; r < 4; ++r) {
              const int qg = q0w + mi * 16 + seg * 4 + r;
              if (kg > qg) s[mi][nf][r] = -1e30f;
            }
          }
      }

      // online softmax (rows = 16-lane col16 groups; butterfly in-group)
#pragma unroll
      for (int mi = 0; mi < 2; ++mi)
#pragma unroll
        for (int r = 0; r < 4; ++r) {
          float pm = fmaxf(fmaxf(s[mi][0][r], s[mi][1][r]),
                           fmaxf(s[mi][2][r], s[mi][3][r]));
#pragma unroll
          for (int x = 1; x < 16; x <<= 1) pm = fmaxf(pm, __shfl_xor(pm, x));
          const float mn = fmaxf(mrow[mi][r], pm);
          const float fs = __expf(mrow[mi][r] - mn);
          mrow[mi][r] = mn;
          float rs = 0.f;
#pragma unroll
          for (int nf = 0; nf < 4; ++nf) {
            s[mi][nf][r] = __expf(s[mi][nf][r] - mn);
            rs += s[mi][nf][r];
          }
#pragma unroll
          for (int x = 1; x < 16; x <<= 1) rs += __shfl_xor(rs, x);
          lsum[mi][r] = lsum[mi][r] * fs + rs;
#pragma unroll
          for (int df = 0; df < 4; ++df) o[mi][df][r] *= fs;
        }

      // PV in two 32-k halves: P -> wave-private swizzled LDS -> A-frags
#pragma unroll
      for (int h = 0; h < 2; ++h) {
#pragma unroll
        for (int nf2 = 0; nf2 < 2; ++nf2) {
          const int nf = h * 2 + nf2;
#pragma unroll
          for (int mi = 0; mi < 2; ++mi)
#pragma unroll
            for (int r = 0; r < 4; ++r) {
              const int prow = mi * 16 + seg * 4 + r;
              const int pcol = nf2 * 16 + col16;
              const int byteoff = prow * 64 + ((pcol * 2) ^ ((prow & 3) << 4));
              *reinterpret_cast<unsigned short*>(myP + byteoff) = f2bf(s[mi][nf][r]);
            }
        }
        short8 pa[2];
#pragma unroll
        for (int mi = 0; mi < 2; ++mi) {
          const int rp = mi * 16 + col16;
          pa[mi] = *reinterpret_cast<const short8*>(
              myP + rp * 64 + ((seg << 4) ^ ((rp & 3) << 4)));
        }
#pragma unroll
        for (int df = 0; df < 4; ++df) {
          const int d = df * 16 + col16;
          const int cc = (h * 4 + seg) ^ (d & 7);
          short8 bv = *reinterpret_cast<const short8*>(
              reinterpret_cast<const char*>(&VsL[cur][0]) + d * 128 + cc * 16);
#pragma unroll
          for (int mi = 0; mi < 2; ++mi)
            o[mi][df] = __builtin_amdgcn_mfma_f32_16x16x32_bf16(pa[mi], bv,
                                                                o[mi][df], 0, 0, 0);
        }
      }
    }

    __syncthreads();  // prefetch landed (vmcnt drain) + all waves done with cur
    cur ^= 1;
  }

  // normalize + store bf16 [B][T][E]
  const int b = bh >> 4;
  const int hh = bh & 15;
#pragma unroll
  for (int mi = 0; mi < 2; ++mi)
#pragma unroll
    for (int r = 0; r < 4; ++r) {
      const float inv = 1.f / lsum[mi][r];
      const int t = q0w + mi * 16 + seg * 4 + r;
#pragma unroll
      for (int df = 0; df < 4; ++df) {
        const int c = hh * 64 + df * 16 + col16;
        Ao[((size_t)(b * TB + t)) * NE + c] = f2bf(o[mi][df][r] * inv);
      }
    }
#undef STAGE_KV
}

// ---------------- launch ----------------
extern "C" void kernel_launch(void* const* d_in, const int* in_sizes, int n_in,
                              void* d_out, int out_size, void* d_ws, size_t ws_size,
                              hipStream_t stream) {
  const float* x = (const float*)d_in[0];
  const float* w_attn = (const float*)d_in[1];
  const float* w_proj = (const float*)d_in[2];
  float* out = (float*)d_out;
  char* ws = (char*)d_ws;

  const size_t SZ_XB = (size_t)MTOK * NE * 2;        // 16 MiB
  const size_t SZ_WA = (size_t)3 * NE * NE * 2;      // 6 MiB
  const size_t SZ_WP = (size_t)NE * NE * 2;          // 2 MiB
  const size_t SZ_T = (size_t)BHD * TB * HD * 2;     // 16 MiB

  unsigned short* xb = (unsigned short*)(ws);
  unsigned short* wab = (unsigned short*)(ws + SZ_XB);
  unsigned short* wpb = (unsigned short*)(ws + SZ_XB + SZ_WA);
  unsigned short* Qs = (unsigned short*)(ws + SZ_XB + SZ_WA + SZ_WP);
  unsigned short* Ks = (unsigned short*)(ws + SZ_XB + SZ_WA + SZ_WP + SZ_T);
  unsigned short* Vt = (unsigned short*)(ws + SZ_XB + SZ_WA + SZ_WP + 2 * SZ_T);
  unsigned short* Ao = (unsigned short*)(ws + SZ_XB + SZ_WA + SZ_WP + 3 * SZ_T);
  // RoPE table lives in Ao's space: needed only by gemm<1>, dead before attn writes Ao
  float2* tab = (float2*)Ao;

  hipLaunchKernelGGL(cvt_kernel, dim3(MTOK * NE / 4 / 256), dim3(256), 0, stream,
                     x, xb, MTOK * NE / 4);
  hipLaunchKernelGGL(cvt_kernel, dim3(3 * NE * NE / 4 / 256), dim3(256), 0, stream,
                     w_attn, wab, 3 * NE * NE / 4);
  hipLaunchKernelGGL(cvt_kernel, dim3(NE * NE / 4 / 256), dim3(256), 0, stream,
                     w_proj, wpb, NE * NE / 4);
  hipLaunchKernelGGL(rope_tab_kernel, dim3(TB * 32 / 256), dim3(256), 0, stream, tab);

  hipLaunchKernelGGL((gemm_bt<1>), dim3(3 * NE / 128, MTOK / 128), dim3(256), 0,
                     stream, xb, wab, nullptr, Qs, Ks, Vt, tab, MTOK, 3 * NE, NE);

  hipLaunchKernelGGL(attn_kernel, dim3(TB / 128, BHD), dim3(256), 0, stream,
                     Qs, Ks, Vt, Ao);

  hipLaunchKernelGGL((gemm_bt<0>), dim3(NE / 128, MTOK / 128), dim3(256), 0,
                     stream, Ao, wpb, out, nullptr, nullptr, nullptr,
                     (const float2*)nullptr, MTOK, NE, NE);
}

// Round 4
// 245.517 us; speedup vs baseline: 3.1625x; 1.3882x over previous
//
#include <hip/hip_runtime.h>
#include <hip/hip_bf16.h>

#define TB 2048
#define NH 16
#define HD 64
#define NE 1024
#define NB 4
#define BHD (NB * NH)      // 64 batch*heads
#define MTOK (NB * TB)     // 8192

typedef __attribute__((ext_vector_type(8))) short short8;
typedef __attribute__((ext_vector_type(4))) float f32x4;
typedef __attribute__((ext_vector_type(16))) float f32x16;
typedef __attribute__((ext_vector_type(4))) unsigned int u32x4;

static __device__ __forceinline__ unsigned short f2bf(float f) {
  __hip_bfloat16 h = __float2bfloat16(f);
  return __builtin_bit_cast(unsigned short, h);
}

#define GLDS(g, l)                                                              \
  __builtin_amdgcn_global_load_lds((const __attribute__((address_space(1))) void*)(g), \
                                   (__attribute__((address_space(3))) void*)(l), 16, 0, 0)

// ---------------- f32 -> bf16 convert (vectorized) ----------------
__global__ __launch_bounds__(256) void cvt_kernel(const float* __restrict__ in,
                                                  unsigned short* __restrict__ out,
                                                  int n4) {
  int i = blockIdx.x * blockDim.x + threadIdx.x;
  if (i >= n4) return;
  float4 v = reinterpret_cast<const float4*>(in)[i];
  ushort4 o;
  o.x = f2bf(v.x); o.y = f2bf(v.y); o.z = f2bf(v.z); o.w = f2bf(v.w);
  reinterpret_cast<ushort4*>(out)[i] = o;
}

// ---------------- RoPE cos/sin table: tab[t*32+j] = (cos, sin)(t * 10000^(-j/32)) ----------------
__global__ __launch_bounds__(256) void rope_tab_kernel(float2* __restrict__ tab) {
  int i = blockIdx.x * 256 + threadIdx.x;  // 0..65535
  int t = i >> 5, j = i & 31;
  float ang = (float)t * __builtin_exp2f(-(float)j * 0.41524101186092029f);
  float sv, cv;
  sincosf(ang, &sv, &cv);
  tab[i] = make_float2(cv, sv);
}

// ---------------- GEMM C = A * B^T (A:[M][K] bf16, B:[N][K] bf16) ----------------
template <int EPI>  // 0: plain f32 C store; 1: QKV epilogue (RoPE + scatter)
__global__ __launch_bounds__(256) void gemm_bt(
    const unsigned short* __restrict__ Am, const unsigned short* __restrict__ Bm,
    float* __restrict__ Cout, unsigned short* __restrict__ Qo,
    unsigned short* __restrict__ Ko, unsigned short* __restrict__ Vt,
    const float2* __restrict__ Tab, int Mdim, int Ndim, int Kdim) {
  __shared__ unsigned short As[128 * 64];
  __shared__ unsigned short Bs[128 * 64];

  const int tid = threadIdx.x;
  const int lane = tid & 63;
  const int w = tid >> 6;
  const int wr = w >> 1;
  const int wc = w & 1;
  const int m0 = blockIdx.y * 128;
  const int n0 = blockIdx.x * 128;
  const int col16 = lane & 15;
  const int seg = lane >> 4;

  f32x4 acc[4][4];
#pragma unroll
  for (int i = 0; i < 4; ++i)
#pragma unroll
    for (int j = 0; j < 4; ++j) acc[i][j] = f32x4{0.f, 0.f, 0.f, 0.f};

  const int lrow = lane >> 3;            // row within 8-row chunk
  const int jg = (lane & 7) ^ lrow;      // pre-swizzled 16B-chunk col in global

  for (int kt = 0; kt < Kdim; kt += 64) {
#pragma unroll
    for (int i = 0; i < 4; ++i) {
      const int q = w * 4 + i;           // 1KB chunk id (0..15)
      const int row = q * 8 + lrow;      // tile row 0..127  (row&7 == lrow)
      GLDS(Am + (size_t)(m0 + row) * Kdim + kt + jg * 8, As + q * 512);
      GLDS(Bm + (size_t)(n0 + row) * Kdim + kt + jg * 8, Bs + q * 512);
    }
    __syncthreads();
#pragma unroll
    for (int kk = 0; kk < 2; ++kk) {
      short8 af[4], bfr[4];
#pragma unroll
      for (int mi = 0; mi < 4; ++mi) {
        const int row = wr * 64 + mi * 16 + col16;
        const int ch = (kk * 4 + seg) ^ (row & 7);
        af[mi] = *reinterpret_cast<const short8*>(
            reinterpret_cast<const char*>(As) + row * 128 + ch * 16);
      }
#pragma unroll
      for (int ni = 0; ni < 4; ++ni) {
        const int row = wc * 64 + ni * 16 + col16;
        const int ch = (kk * 4 + seg) ^ (row & 7);
        bfr[ni] = *reinterpret_cast<const short8*>(
            reinterpret_cast<const char*>(Bs) + row * 128 + ch * 16);
      }
#pragma unroll
      for (int mi = 0; mi < 4; ++mi)
#pragma unroll
        for (int ni = 0; ni < 4; ++ni)
          acc[mi][ni] = __builtin_amdgcn_mfma_f32_16x16x32_bf16(af[mi], bfr[ni],
                                                                acc[mi][ni], 0, 0, 0);
    }
    __syncthreads();
  }

  if (EPI == 0) {
#pragma unroll
    for (int mi = 0; mi < 4; ++mi)
#pragma unroll
      for (int ni = 0; ni < 4; ++ni) {
        const int gn = n0 + wc * 64 + ni * 16 + col16;
#pragma unroll
        for (int r = 0; r < 4; ++r) {
          const int gm = m0 + wr * 64 + mi * 16 + seg * 4 + r;
          Cout[(size_t)gm * Ndim + gn] = acc[mi][ni][r];
        }
      }
  } else {
    // qkv: n in [0,1024)=Q, [1024,2048)=K, [2048,3072)=V. 128|1024 so sec uniform.
    const int sec = n0 >> 10;
    const int cbase = (n0 & 1023) + wc * 64;  // multiple of 64
    const int h = cbase >> 6;
#pragma unroll
    for (int mi = 0; mi < 4; ++mi)
#pragma unroll
      for (int ni = 0; ni < 4; ++ni) {
        const int d = ni * 16 + col16;  // 0..63 head dim
        if (sec == 2) {
          // V: store transposed [BH][D][T]; 4 consecutive t per lane -> 8B store
          const int gm0 = m0 + wr * 64 + mi * 16 + seg * 4;
          const int b = gm0 >> 11;
          const int t0 = gm0 & 2047;
          ushort4 pv;
          pv.x = f2bf(acc[mi][ni][0]);
          pv.y = f2bf(acc[mi][ni][1]);
          pv.z = f2bf(acc[mi][ni][2]);
          pv.w = f2bf(acc[mi][ni][3]);
          *reinterpret_cast<ushort4*>(
              Vt + ((size_t)((b * NH + h) * HD + d)) * TB + t0) = pv;
        } else {
          // RoPE via precomputed table: angle a_d = t * 10000^(-(d%32)/32)
          const float sgn = (d & 1) ? 1.f : -1.f;
          const int j = d & 31;
#pragma unroll
          for (int r = 0; r < 4; ++r) {
            const int gm = m0 + wr * 64 + mi * 16 + seg * 4 + r;
            const int b = gm >> 11;
            const int t = gm & 2047;
            const float v = acc[mi][ni][r];
            const float p = __shfl_xor(v, 1);  // pair partner (adjacent col)
            const float2 csv = Tab[t * 32 + j];
            float rot = v * csv.x + sgn * p * csv.y;
            // fold 1/sqrt(D) AND log2(e) into Q so attn softmax can use exp2
            if (sec == 0) rot *= 0.18033688011112042f;  // 0.125 * log2(e)
            unsigned short* dst = (sec == 0) ? Qo : Ko;
            dst[((size_t)(b * NH + h) * TB + t) * HD + d] = f2bf(rot);
          }
        }
      }
  }
}

// ---------------- causal flash attention v2: swapped-operand 32x32, no LDS ----------------
// One wave per 32-q tile. S^T = mfma32x32x16(K, Q) -> lane holds P-row for q=lane&31
// (kv rows (r&3)+8*(r>>2)+4*hi in 16 regs; partner lane^32 has the other 16).
// Softmax fully in-register. PV as O^T = mfma(V^T, P^T) so rescale factor is
// lane-uniform. K frags from K[BH][T][D], V frags from Vt[BH][D][T]: contiguous
// 16B global loads (L2-resident). No LDS, no barriers; waves independent.
__global__ __launch_bounds__(256) void attn_kernel(
    const unsigned short* __restrict__ Q, const unsigned short* __restrict__ K,
    const unsigned short* __restrict__ Vt, unsigned short* __restrict__ Ao) {
  const int tid = threadIdx.x;
  const int lane = tid & 63;
  const int w = tid >> 6;
  const int b = blockIdx.x;
  const int bh = ((b & 15) << 2) | w;   // 4 waves of a block share qt (equal length)
  const int qt = 63 - (b >> 4);         // longest q-tiles dispatched first
  const int q0 = qt << 5;
  const int l31 = lane & 31;
  const int hi = lane >> 5;
  const int qm = l31 - 4 * hi;          // diag mask: kill reg r if rowbase(r) > qm

  const unsigned short* Qp = Q + (size_t)bh * TB * HD + (size_t)(q0 + l31) * HD + hi * 8;
  const unsigned short* Kp = K + (size_t)bh * TB * HD + (size_t)l31 * HD + hi * 8;
  const unsigned short* Vp = Vt + (size_t)bh * HD * TB + (size_t)l31 * TB + hi * 8;

  short8 qf[4];
#pragma unroll
  for (int s = 0; s < 4; ++s)
    qf[s] = *reinterpret_cast<const short8*>(Qp + s * 16);

  f32x16 o0, o1;
#pragma unroll
  for (int r = 0; r < 16; ++r) { o0[r] = 0.f; o1[r] = 0.f; }
  float mrow = -1e30f, lsum = 0.f;

#define MASKDIAG(st)                                                            \
  { _Pragma("unroll") for (int r = 0; r < 16; ++r) {                            \
      const int rowb = (r & 3) + 8 * (r >> 2);                                  \
      if (rowb > qm) st[r] = -1e30f; } }

  // PV for one 32-kv S-tile: pack P to bf16 words, build P^T B-frags via
  // lane<->lane^32 word exchange, then O^T += V^T * P^T.
#define PVTILE(st, kvb)                                                         \
  {                                                                             \
    unsigned int wd[8];                                                         \
    _Pragma("unroll") for (int i = 0; i < 8; ++i)                               \
      wd[i] = (unsigned int)f2bf(st[2 * i]) |                                   \
              ((unsigned int)f2bf(st[2 * i + 1]) << 16);                        \
    unsigned int ex0 = __shfl_xor(hi ? wd[0] : wd[2], 32);                      \
    unsigned int ex1 = __shfl_xor(hi ? wd[1] : wd[3], 32);                      \
    unsigned int ex2 = __shfl_xor(hi ? wd[4] : wd[6], 32);                      \
    unsigned int ex3 = __shfl_xor(hi ? wd[5] : wd[7], 32);                      \
    u32x4 f0, f1;                                                               \
    f0[0] = hi ? ex0 : wd[0]; f0[1] = hi ? ex1 : wd[1];                         \
    f0[2] = hi ? wd[2] : ex0; f0[3] = hi ? wd[3] : ex1;                         \
    f1[0] = hi ? ex2 : wd[4]; f1[1] = hi ? ex3 : wd[5];                         \
    f1[2] = hi ? wd[6] : ex2; f1[3] = hi ? wd[7] : ex3;                         \
    short8 p0 = __builtin_bit_cast(short8, f0);                                 \
    short8 p1 = __builtin_bit_cast(short8, f1);                                 \
    short8 v00 = *reinterpret_cast<const short8*>(Vp + (kvb));                  \
    short8 v01 = *reinterpret_cast<const short8*>(Vp + 32 * TB + (kvb));        \
    short8 v10 = *reinterpret_cast<const short8*>(Vp + (kvb) + 16);             \
    short8 v11 = *reinterpret_cast<const short8*>(Vp + 32 * TB + (kvb) + 16);   \
    __builtin_amdgcn_s_setprio(1);                                              \
    o0 = __builtin_amdgcn_mfma_f32_32x32x16_bf16(v00, p0, o0, 0, 0, 0);         \
    o1 = __builtin_amdgcn_mfma_f32_32x32x16_bf16(v01, p0, o1, 0, 0, 0);         \
    o0 = __builtin_amdgcn_mfma_f32_32x32x16_bf16(v10, p1, o0, 0, 0, 0);         \
    o1 = __builtin_amdgcn_mfma_f32_32x32x16_bf16(v11, p1, o1, 0, 0, 0);         \
    __builtin_amdgcn_s_setprio(0);                                              \
  }

  const int L = qt >> 1;
  for (int kt = 0; kt <= L; ++kt) {
    const int kv0 = kt << 6;
    const bool two = (kv0 + 32 <= q0);  // second 32-kv S-tile active

    // K fragments + QK^T (S^T accumulate)
    short8 kf0[4], kf1[4];
#pragma unroll
    for (int s = 0; s < 4; ++s)
      kf0[s] = *reinterpret_cast<const short8*>(Kp + (size_t)kv0 * HD + s * 16);
    if (two)
#pragma unroll
      for (int s = 0; s < 4; ++s)
        kf1[s] = *reinterpret_cast<const short8*>(Kp + (size_t)(kv0 + 32) * HD + s * 16);

    f32x16 s0, s1;
#pragma unroll
    for (int r = 0; r < 16; ++r) { s0[r] = 0.f; s1[r] = 0.f; }
    __builtin_amdgcn_s_setprio(1);
#pragma unroll
    for (int s = 0; s < 4; ++s)
      s0 = __builtin_amdgcn_mfma_f32_32x32x16_bf16(kf0[s], qf[s], s0, 0, 0, 0);
    if (two)
#pragma unroll
      for (int s = 0; s < 4; ++s)
        s1 = __builtin_amdgcn_mfma_f32_32x32x16_bf16(kf1[s], qf[s], s1, 0, 0, 0);
    __builtin_amdgcn_s_setprio(0);

    // causal mask on the diagonal 32x32 tile (kvb == q0)
    if (kv0 == q0) MASKDIAG(s0);
    if (two && (kv0 + 32 == q0)) MASKDIAG(s1);

    // online softmax (values in exp2 domain; Q pre-scaled by 0.125*log2e)
    float pm = s0[0];
#pragma unroll
    for (int r = 1; r < 16; ++r) pm = fmaxf(pm, s0[r]);
    if (two)
#pragma unroll
      for (int r = 0; r < 16; ++r) pm = fmaxf(pm, s1[r]);
    pm = fmaxf(pm, __shfl_xor(pm, 32));
    const float mn = fmaxf(mrow, pm);
    const float fs = __builtin_exp2f(mrow - mn);
    mrow = mn;
    float rs = 0.f;
#pragma unroll
    for (int r = 0; r < 16; ++r) { s0[r] = __builtin_exp2f(s0[r] - mn); rs += s0[r]; }
    if (two)
#pragma unroll
      for (int r = 0; r < 16; ++r) { s1[r] = __builtin_exp2f(s1[r] - mn); rs += s1[r]; }
    rs += __shfl_xor(rs, 32);
    lsum = lsum * fs + rs;
#pragma unroll
    for (int r = 0; r < 16; ++r) { o0[r] *= fs; o1[r] *= fs; }

    PVTILE(s0, kv0);
    if (two) PVTILE(s1, kv0 + 32);
  }

  // epilogue: normalize (lsum lane-uniform) and store bf16 to Ao[B][T][E]
  const float inv = 1.f / lsum;
  const int batch = bh >> 4;
  const int h = bh & 15;
  unsigned short* Aor = Ao + ((size_t)(batch * TB + q0 + l31)) * NE + (h << 6);
#pragma unroll
  for (int dt = 0; dt < 2; ++dt) {
#pragma unroll
    for (int qd = 0; qd < 4; ++qd) {
      ushort4 pk;
      pk.x = f2bf((dt ? o1[4 * qd + 0] : o0[4 * qd + 0]) * inv);
      pk.y = f2bf((dt ? o1[4 * qd + 1] : o0[4 * qd + 1]) * inv);
      pk.z = f2bf((dt ? o1[4 * qd + 2] : o0[4 * qd + 2]) * inv);
      pk.w = f2bf((dt ? o1[4 * qd + 3] : o0[4 * qd + 3]) * inv);
      *reinterpret_cast<ushort4*>(Aor + dt * 32 + 8 * qd + 4 * hi) = pk;
    }
  }
#undef MASKDIAG
#undef PVTILE
}

// ---------------- launch ----------------
extern "C" void kernel_launch(void* const* d_in, const int* in_sizes, int n_in,
                              void* d_out, int out_size, void* d_ws, size_t ws_size,
                              hipStream_t stream) {
  const float* x = (const float*)d_in[0];
  const float* w_attn = (const float*)d_in[1];
  const float* w_proj = (const float*)d_in[2];
  float* out = (float*)d_out;
  char* ws = (char*)d_ws;

  const size_t SZ_XB = (size_t)MTOK * NE * 2;        // 16 MiB
  const size_t SZ_WA = (size_t)3 * NE * NE * 2;      // 6 MiB
  const size_t SZ_WP = (size_t)NE * NE * 2;          // 2 MiB
  const size_t SZ_T = (size_t)BHD * TB * HD * 2;     // 16 MiB

  unsigned short* xb = (unsigned short*)(ws);
  unsigned short* wab = (unsigned short*)(ws + SZ_XB);
  unsigned short* wpb = (unsigned short*)(ws + SZ_XB + SZ_WA);
  unsigned short* Qs = (unsigned short*)(ws + SZ_XB + SZ_WA + SZ_WP);
  unsigned short* Ks = (unsigned short*)(ws + SZ_XB + SZ_WA + SZ_WP + SZ_T);
  unsigned short* Vt = (unsigned short*)(ws + SZ_XB + SZ_WA + SZ_WP + 2 * SZ_T);
  unsigned short* Ao = (unsigned short*)(ws + SZ_XB + SZ_WA + SZ_WP + 3 * SZ_T);
  // RoPE table lives in Ao's space: needed only by gemm<1>, dead before attn writes Ao
  float2* tab = (float2*)Ao;

  hipLaunchKernelGGL(cvt_kernel, dim3(MTOK * NE / 4 / 256), dim3(256), 0, stream,
                     x, xb, MTOK * NE / 4);
  hipLaunchKernelGGL(cvt_kernel, dim3(3 * NE * NE / 4 / 256), dim3(256), 0, stream,
                     w_attn, wab, 3 * NE * NE / 4);
  hipLaunchKernelGGL(cvt_kernel, dim3(NE * NE / 4 / 256), dim3(256), 0, stream,
                     w_proj, wpb, NE * NE / 4);
  hipLaunchKernelGGL(rope_tab_kernel, dim3(TB * 32 / 256), dim3(256), 0, stream, tab);

  hipLaunchKernelGGL((gemm_bt<1>), dim3(3 * NE / 128, MTOK / 128), dim3(256), 0,
                     stream, xb, wab, nullptr, Qs, Ks, Vt, tab, MTOK, 3 * NE, NE);

  // (T/32 q-tiles) * BHD waves / 4 waves-per-block = 1024 blocks
  hipLaunchKernelGGL(attn_kernel, dim3((TB / 32) * BHD / 4), dim3(256), 0, stream,
                     Qs, Ks, Vt, Ao);

  hipLaunchKernelGGL((gemm_bt<0>), dim3(NE / 128, MTOK / 128), dim3(256), 0,
                     stream, Ao, wpb, out, nullptr, nullptr, nullptr,
                     (const float2*)nullptr, MTOK, NE, NE);
}